// Round 2
// baseline (945.546 us; speedup 1.0000x reference)
//
#include <hip/hip_runtime.h>
#include <hip/hip_bf16.h>
#include <stdint.h>

#define M_MOL 128
#define L_SEQ 256
#define H_DIM 768
#define NH_   12
#define HD_   64
#define N_TOT (M_MOL * L_SEQ)

typedef __attribute__((ext_vector_type(8))) short bf16x8;
typedef __attribute__((ext_vector_type(4))) float f32x4;
typedef __attribute__((ext_vector_type(8))) unsigned short u16x8;
typedef __hip_bfloat16 bf16;

__device__ __forceinline__ float bf2f(bf16 x){ return __bfloat162float(x); }
__device__ __forceinline__ bf16 f2bf(float x){ return __float2bfloat16(x); }
__device__ __forceinline__ float bfbits2f(unsigned short u){
    return __uint_as_float(((unsigned)u) << 16);
}
__device__ __forceinline__ unsigned pk2(float lo, float hi){
    bf16 a = f2bf(lo), b = f2bf(hi);
    unsigned short ua, ub;
    __builtin_memcpy(&ua, &a, 2);
    __builtin_memcpy(&ub, &b, 2);
    return (unsigned)ua | ((unsigned)ub << 16);
}

// C[n][o] = sum_k A[n][k] * B[o][k] + bias[o]; A: f32 or bf16 (template), B: f32
// grid: (rows/128, cols/128), block 256 = 4 waves, each computing 64x64
template<bool A_IS_F32>
__global__ __launch_bounds__(256, 2)
void gemm_bt(const void* __restrict__ Av, const float* __restrict__ B,
             const float* __restrict__ bias, bf16* __restrict__ C)
{
    // LDS row stride 56 bf16 = 112B -> 16B-aligned ds_read_b128, ~2-way banks (free)
    __shared__ __align__(16) bf16 As[128*56];
    __shared__ __align__(16) bf16 Bs[128*56];
    const int t = threadIdx.x;
    const int rowBase = blockIdx.x * 128;
    const int colBase = blockIdx.y * 128;
    const int w = t >> 6, lane = t & 63, quad = lane >> 4, r16 = lane & 15;
    const int wr = w >> 1, wc = w & 1;

    f32x4 acc[4][4];
#pragma unroll
    for (int i = 0; i < 4; ++i)
#pragma unroll
        for (int j = 0; j < 4; ++j) acc[i][j] = (f32x4){0.f, 0.f, 0.f, 0.f};

    const int srow = t >> 1, shalf = t & 1;   // staging: 128 rows x 2 halves of 16
    for (int k0 = 0; k0 < 768; k0 += 32) {
        if constexpr (A_IS_F32) {
            const float* src = (const float*)Av + (size_t)(rowBase+srow)*768 + k0 + shalf*16;
            float4 f0 = *(const float4*)(src);
            float4 f1 = *(const float4*)(src + 4);
            float4 f2 = *(const float4*)(src + 8);
            float4 f3 = *(const float4*)(src + 12);
            uint4 lo = { pk2(f0.x,f0.y), pk2(f0.z,f0.w), pk2(f1.x,f1.y), pk2(f1.z,f1.w) };
            uint4 hi = { pk2(f2.x,f2.y), pk2(f2.z,f2.w), pk2(f3.x,f3.y), pk2(f3.z,f3.w) };
            *(uint4*)(&As[srow*56 + shalf*16])     = lo;
            *(uint4*)(&As[srow*56 + shalf*16 + 8]) = hi;
        } else {
#pragma unroll
            for (int i = 0; i < 2; ++i) {
                int u = t + i * 256;
                int row = u >> 2, cu = u & 3;
                *(uint4*)(&As[row*56 + cu*8]) =
                    *(const uint4*)((const bf16*)Av + (size_t)(rowBase+row)*768 + k0 + cu*8);
            }
        }
        {
            const float* src = B + (size_t)(colBase+srow)*768 + k0 + shalf*16;
            float4 f0 = *(const float4*)(src);
            float4 f1 = *(const float4*)(src + 4);
            float4 f2 = *(const float4*)(src + 8);
            float4 f3 = *(const float4*)(src + 12);
            uint4 lo = { pk2(f0.x,f0.y), pk2(f0.z,f0.w), pk2(f1.x,f1.y), pk2(f1.z,f1.w) };
            uint4 hi = { pk2(f2.x,f2.y), pk2(f2.z,f2.w), pk2(f3.x,f3.y), pk2(f3.z,f3.w) };
            *(uint4*)(&Bs[srow*56 + shalf*16])     = lo;
            *(uint4*)(&Bs[srow*56 + shalf*16 + 8]) = hi;
        }
        __syncthreads();
        bf16x8 af[4], bfr[4];
#pragma unroll
        for (int ti = 0; ti < 4; ++ti)
            af[ti] = *(const bf16x8*)(&As[(wr*64 + ti*16 + r16)*56 + quad*8]);
#pragma unroll
        for (int tj = 0; tj < 4; ++tj)
            bfr[tj] = *(const bf16x8*)(&Bs[(wc*64 + tj*16 + r16)*56 + quad*8]);
#pragma unroll
        for (int ti = 0; ti < 4; ++ti)
#pragma unroll
            for (int tj = 0; tj < 4; ++tj)
                acc[ti][tj] = __builtin_amdgcn_mfma_f32_16x16x32_bf16(
                    af[ti], bfr[tj], acc[ti][tj], 0, 0, 0);
        __syncthreads();
    }
    // epilogue: C/D layout col = lane&15, row = quad*4 + reg
#pragma unroll
    for (int tj = 0; tj < 4; ++tj) {
        int col = colBase + wc*64 + tj*16 + r16;
        float bv = bias[col];
#pragma unroll
        for (int ti = 0; ti < 4; ++ti) {
            int row0 = rowBase + wr*64 + ti*16 + quad*4;
#pragma unroll
            for (int rr = 0; rr < 4; ++rr)
                C[(size_t)(row0+rr)*768 + col] = f2bf(acc[ti][tj][rr] + bv);
        }
    }
}

// one block = (m, nh, 32-q-row strip); 128 threads = 2 waves x 16 q rows
__global__ __launch_bounds__(128, 2)
void attn_kernel(const bf16* __restrict__ qbuf, const bf16* __restrict__ kbuf,
                 const bf16* __restrict__ vbuf, const int* __restrict__ a_sizes,
                 bf16* __restrict__ cbuf)
{
    __shared__ __align__(16) bf16 VT[64*264];      // V^T [d][key], stride 264
    __shared__ __align__(16) bf16 P[2*16*264];     // per-wave prob strips

    const int b = blockIdx.x;
    const int m   = b / (NH_*8);
    const int rem = b % (NH_*8);
    const int nh  = rem >> 3;
    const int qt  = rem & 7;
    const int t = threadIdx.x;
    const int w = t >> 6, lane = t & 63, quad = lane >> 4, r16 = lane & 15;
    const int size = a_sizes[m];

    // stage V^T: thread t handles keys 2t, 2t+1
    {
        const bf16* v0 = vbuf + ((size_t)(m*L_SEQ + 2*t))*768 + nh*64;
        const bf16* v1 = v0 + 768;
#pragma unroll
        for (int d0 = 0; d0 < 64; d0 += 8) {
            u16x8 a = *(const u16x8*)(v0 + d0);
            u16x8 c = *(const u16x8*)(v1 + d0);
#pragma unroll
            for (int j = 0; j < 8; ++j) {
                unsigned val = (unsigned)a[j] | ((unsigned)c[j] << 16);
                *(unsigned*)(&VT[(d0+j)*264 + 2*t]) = val;
            }
        }
    }
    __syncthreads();

    const int qbase = qt*32 + w*16;
    bf16x8 aq0, aq1;
    {
        const bf16* qrow = qbuf + ((size_t)(m*L_SEQ + qbase + r16))*768 + nh*64 + quad*8;
        aq0 = *(const bf16x8*)(qrow);
        aq1 = *(const bf16x8*)(qrow + 32);
    }
    f32x4 S[16];
#pragma unroll
    for (int kt = 0; kt < 16; ++kt) {
        const bf16* krow = kbuf + ((size_t)(m*L_SEQ + kt*16 + r16))*768 + nh*64 + quad*8;
        bf16x8 bk0 = *(const bf16x8*)(krow);
        bf16x8 bk1 = *(const bf16x8*)(krow + 32);
        f32x4 s = (f32x4){0.f, 0.f, 0.f, 0.f};
        s = __builtin_amdgcn_mfma_f32_16x16x32_bf16(aq0, bk0, s, 0, 0, 0);
        s = __builtin_amdgcn_mfma_f32_16x16x32_bf16(aq1, bk1, s, 0, 0, 0);
        S[kt] = s;
    }
    float mrow[4] = {-1e30f, -1e30f, -1e30f, -1e30f};
#pragma unroll
    for (int kt = 0; kt < 16; ++kt) {
        int key = kt*16 + r16;
#pragma unroll
        for (int rr = 0; rr < 4; ++rr) {
            float s = S[kt][rr] * 0.125f;
            if (key >= size) s = -1e9f;
            S[kt][rr] = s;
            mrow[rr] = fmaxf(mrow[rr], s);
        }
    }
#pragma unroll
    for (int msk = 1; msk < 16; msk <<= 1)
#pragma unroll
        for (int rr = 0; rr < 4; ++rr)
            mrow[rr] = fmaxf(mrow[rr], __shfl_xor(mrow[rr], msk));
    float lrow[4] = {0.f, 0.f, 0.f, 0.f};
    bf16* Pw = P + w*16*264;
#pragma unroll
    for (int kt = 0; kt < 16; ++kt) {
#pragma unroll
        for (int rr = 0; rr < 4; ++rr) {
            float p = __expf(S[kt][rr] - mrow[rr]);
            lrow[rr] += p;
            Pw[(quad*4+rr)*264 + kt*16 + r16] = f2bf(p);
        }
    }
#pragma unroll
    for (int msk = 1; msk < 16; msk <<= 1)
#pragma unroll
        for (int rr = 0; rr < 4; ++rr)
            lrow[rr] += __shfl_xor(lrow[rr], msk);
    __syncthreads();

    bf16x8 pa[8];
#pragma unroll
    for (int kb2 = 0; kb2 < 8; ++kb2)
        pa[kb2] = *(const bf16x8*)(&Pw[r16*264 + kb2*32 + quad*8]);
    float inv[4];
#pragma unroll
    for (int rr = 0; rr < 4; ++rr) inv[rr] = 1.f / lrow[rr];
#pragma unroll
    for (int dt = 0; dt < 4; ++dt) {
        f32x4 c = (f32x4){0.f, 0.f, 0.f, 0.f};
#pragma unroll
        for (int kb2 = 0; kb2 < 8; ++kb2) {
            bf16x8 vb8 = *(const bf16x8*)(&VT[(dt*16 + r16)*264 + kb2*32 + quad*8]);
            c = __builtin_amdgcn_mfma_f32_16x16x32_bf16(pa[kb2], vb8, c, 0, 0, 0);
        }
#pragma unroll
        for (int rr = 0; rr < 4; ++rr) {
            int q = qbase + quad*4 + rr;
            cbuf[((size_t)(m*L_SEQ + q))*768 + nh*64 + dt*16 + r16] =
                f2bf(c[rr] * inv[rr]);
        }
    }
}

// residual + LayerNorm + mask; wave per row; f32 in/out, proj is bf16
__global__ __launch_bounds__(256, 4)
void ln_kernel(const bf16* __restrict__ proj, const float* __restrict__ af,
               const float* __restrict__ gamma, const float* __restrict__ beta,
               const int* __restrict__ a_sizes, float* __restrict__ out)
{
    const int w = threadIdx.x >> 6, lane = threadIdx.x & 63;
    const int n = blockIdx.x * 4 + w;
    const int m = n >> 8, l = n & 255;
    const int size = a_sizes[m];
    float* orow = out + (size_t)n * 768;
    if (l >= size) {
        float4 z = {0.f, 0.f, 0.f, 0.f};
#pragma unroll
        for (int i = 0; i < 3; ++i)
            *(float4*)(&orow[i*256 + lane*4]) = z;
        return;
    }
    const bf16*  prow = proj + (size_t)n * 768;
    const float* xrow = af   + (size_t)n * 768;
    float y[3][4];
    float s = 0.f;
#pragma unroll
    for (int i = 0; i < 3; ++i) {
        int c = i*256 + lane*4;
        float4 xv = *(const float4*)(&xrow[c]);
        ushort4 pv = *(const ushort4*)(&prow[c]);
        y[i][0] = xv.x + bfbits2f(pv.x);
        y[i][1] = xv.y + bfbits2f(pv.y);
        y[i][2] = xv.z + bfbits2f(pv.z);
        y[i][3] = xv.w + bfbits2f(pv.w);
        s += y[i][0] + y[i][1] + y[i][2] + y[i][3];
    }
#pragma unroll
    for (int msk = 1; msk < 64; msk <<= 1) s += __shfl_xor(s, msk);
    float mu = s * (1.f/768.f);
    float v = 0.f;
#pragma unroll
    for (int i = 0; i < 3; ++i)
#pragma unroll
        for (int j = 0; j < 4; ++j) { float d = y[i][j] - mu; v += d*d; }
#pragma unroll
    for (int msk = 1; msk < 64; msk <<= 1) v += __shfl_xor(v, msk);
    float rstd = rsqrtf(v * (1.f/768.f) + 1e-5f);
#pragma unroll
    for (int i = 0; i < 3; ++i) {
        int c = i*256 + lane*4;
        float4 gv = *(const float4*)(&gamma[c]);
        float4 bv = *(const float4*)(&beta[c]);
        float4 o;
        o.x = (y[i][0] - mu) * rstd * gv.x + bv.x;
        o.y = (y[i][1] - mu) * rstd * gv.y + bv.y;
        o.z = (y[i][2] - mu) * rstd * gv.z + bv.z;
        o.w = (y[i][3] - mu) * rstd * gv.w + bv.w;
        *(float4*)(&orow[c]) = o;
    }
}

extern "C" void kernel_launch(void* const* d_in, const int* in_sizes, int n_in,
                              void* d_out, int out_size, void* d_ws, size_t ws_size,
                              hipStream_t stream)
{
    (void)in_sizes; (void)n_in; (void)out_size; (void)ws_size;
    const float* af    = (const float*)d_in[0];
    const float* Wq    = (const float*)d_in[1];
    const float* bq    = (const float*)d_in[2];
    const float* Wk    = (const float*)d_in[3];
    const float* bk    = (const float*)d_in[4];
    const float* Wv    = (const float*)d_in[5];
    const float* bv    = (const float*)d_in[6];
    const float* Wo    = (const float*)d_in[7];
    const float* bo    = (const float*)d_in[8];
    const float* gamma = (const float*)d_in[9];
    const float* beta  = (const float*)d_in[10];
    const int* a_sizes = (const int*)d_in[12];
    float* outp = (float*)d_out;

    // workspace: q, k, v, ctx (bf16, N x 768 each) = 192 MiB; proj reuses q
    bf16* qb = (bf16*)d_ws;
    bf16* kb = qb + (size_t)N_TOT * 768;
    bf16* vb = kb + (size_t)N_TOT * 768;
    bf16* cb = vb + (size_t)N_TOT * 768;

    dim3 gg(N_TOT / 128, 6), bb(256);
    gemm_bt<true><<<gg, bb, 0, stream>>>(af, Wq, bq, qb);
    gemm_bt<true><<<gg, bb, 0, stream>>>(af, Wk, bk, kb);
    gemm_bt<true><<<gg, bb, 0, stream>>>(af, Wv, bv, vb);
    attn_kernel<<<dim3(M_MOL * NH_ * 8), dim3(128), 0, stream>>>(qb, kb, vb, a_sizes, cb);
    gemm_bt<false><<<gg, bb, 0, stream>>>(cb, Wo, bo, qb);   // proj overwrites q buffer
    ln_kernel<<<dim3(N_TOT / 4), dim3(256), 0, stream>>>(qb, af, gamma, beta, a_sizes, outp);
}

// Round 3
// 619.916 us; speedup vs baseline: 1.5253x; 1.5253x over previous
//
#include <hip/hip_runtime.h>
#include <hip/hip_bf16.h>
#include <stdint.h>

#define M_MOL 128
#define L_SEQ 256
#define H_DIM 768
#define NH_   12
#define HD_   64
#define N_TOT (M_MOL * L_SEQ)

typedef __attribute__((ext_vector_type(8))) short bf16x8;
typedef __attribute__((ext_vector_type(4))) float f32x4;
typedef __attribute__((ext_vector_type(8))) unsigned short u16x8;
typedef __hip_bfloat16 bf16;

__device__ __forceinline__ float bf2f(bf16 x){ return __bfloat162float(x); }
__device__ __forceinline__ bf16 f2bf(float x){ return __float2bfloat16(x); }
__device__ __forceinline__ float bfbits2f(unsigned short u){
    return __uint_as_float(((unsigned)u) << 16);
}
__device__ __forceinline__ unsigned pk2(float lo, float hi){
    bf16 a = f2bf(lo), b = f2bf(hi);
    unsigned short ua, ub;
    __builtin_memcpy(&ua, &a, 2);
    __builtin_memcpy(&ub, &b, 2);
    return (unsigned)ua | ((unsigned)ub << 16);
}

typedef const __attribute__((address_space(1))) unsigned int* as1_u32p;
typedef __attribute__((address_space(3))) unsigned int* as3_u32p;
__device__ __forceinline__ void async_ld16(const void* g, const void* l) {
    __builtin_amdgcn_global_load_lds((as1_u32p)(unsigned long long)g,
                                     (as3_u32p)(unsigned int)(unsigned long long)l,
                                     16, 0, 0);
}

__global__ __launch_bounds__(256)
void cvt_w(const float* __restrict__ Wq, const float* __restrict__ Wk,
           const float* __restrict__ Wv, const float* __restrict__ Wo,
           bf16* __restrict__ Wcat, bf16* __restrict__ Wobf)
{
    const int matId = blockIdx.y;
    const float* src = matId==0 ? Wq : matId==1 ? Wk : matId==2 ? Wv : Wo;
    bf16* dst = (matId < 3) ? (Wcat + (size_t)matId*589824) : Wobf;
    const size_t off = ((size_t)blockIdx.x*256 + threadIdx.x)*8;
    float4 a = *(const float4*)(src + off);
    float4 b = *(const float4*)(src + off + 4);
    uint4 o = { pk2(a.x,a.y), pk2(a.z,a.w), pk2(b.x,b.y), pk2(b.z,b.w) };
    *(uint4*)(dst + off) = o;
}

// fused QKV GEMM; grid (18, 256): x = col-block, y = row-block
__global__ __launch_bounds__(256, 2)
void gemm_qkv(const float* __restrict__ A, const bf16* __restrict__ W,
              const float* __restrict__ bq, const float* __restrict__ bk,
              const float* __restrict__ bv,
              bf16* __restrict__ qb, bf16* __restrict__ kb, bf16* __restrict__ vb)
{
    __shared__ __align__(16) bf16 As[128*40];
    __shared__ __align__(16) bf16 Bs[128*32];
    const int t = threadIdx.x;
    const int colBase = blockIdx.x * 128;
    const int rowBase = blockIdx.y * 128;
    const int w = t >> 6, lane = t & 63, quad = lane >> 4, r16 = lane & 15;
    const int wr = w >> 1, wc = w & 1;
    const int srow = t >> 1, shalf = t & 1;
    const int ldsW = w << 6;

    f32x4 acc[4][4];
#pragma unroll
    for (int i = 0; i < 4; ++i)
#pragma unroll
        for (int j = 0; j < 4; ++j) acc[i][j] = (f32x4){0.f,0.f,0.f,0.f};

    for (int k0 = 0; k0 < 768; k0 += 32) {
        {
            int u0 = t, u1 = t + 256;
            async_ld16(&W[(size_t)(colBase + (u0>>2))*768 + k0 + (u0&3)*8],
                       &Bs[(size_t)ldsW*8]);
            async_ld16(&W[(size_t)(colBase + (u1>>2))*768 + k0 + (u1&3)*8],
                       &Bs[(size_t)(256 + ldsW)*8]);
        }
        {
            const float* src = A + (size_t)(rowBase+srow)*768 + k0 + shalf*16;
            float4 f0 = *(const float4*)(src);
            float4 f1 = *(const float4*)(src + 4);
            float4 f2 = *(const float4*)(src + 8);
            float4 f3 = *(const float4*)(src + 12);
            uint4 lo = { pk2(f0.x,f0.y), pk2(f0.z,f0.w), pk2(f1.x,f1.y), pk2(f1.z,f1.w) };
            uint4 hi = { pk2(f2.x,f2.y), pk2(f2.z,f2.w), pk2(f3.x,f3.y), pk2(f3.z,f3.w) };
            *(uint4*)(&As[srow*40 + shalf*16])     = lo;
            *(uint4*)(&As[srow*40 + shalf*16 + 8]) = hi;
        }
        __syncthreads();
        bf16x8 af[4], bfr[4];
#pragma unroll
        for (int ti = 0; ti < 4; ++ti)
            af[ti] = *(const bf16x8*)(&As[(wr*64 + ti*16 + r16)*40 + quad*8]);
#pragma unroll
        for (int tj = 0; tj < 4; ++tj)
            bfr[tj] = *(const bf16x8*)(&Bs[(wc*64 + tj*16 + r16)*32 + quad*8]);
#pragma unroll
        for (int ti = 0; ti < 4; ++ti)
#pragma unroll
            for (int tj = 0; tj < 4; ++tj)
                acc[ti][tj] = __builtin_amdgcn_mfma_f32_16x16x32_bf16(
                    af[ti], bfr[tj], acc[ti][tj], 0, 0, 0);
        __syncthreads();
    }
    const int sel = blockIdx.x / 6;
    const float* bias = sel==0 ? bq : sel==1 ? bk : bv;
    bf16* C = sel==0 ? qb : sel==1 ? kb : vb;
    const int colSec = colBase - sel*768;
#pragma unroll
    for (int tj = 0; tj < 4; ++tj) {
        int col = colSec + wc*64 + tj*16 + r16;
        float bb = bias[col];
#pragma unroll
        for (int ti = 0; ti < 4; ++ti) {
            int row0 = rowBase + wr*64 + ti*16 + quad*4;
#pragma unroll
            for (int rr = 0; rr < 4; ++rr)
                C[(size_t)(row0+rr)*768 + col] = f2bf(acc[ti][tj][rr] + bb);
        }
    }
}

// all-bf16 GEMM (Wo projection); grid (6, 256)
__global__ __launch_bounds__(256, 2)
void gemm_o(const bf16* __restrict__ A, const bf16* __restrict__ W,
            const float* __restrict__ bo, bf16* __restrict__ C)
{
    __shared__ __align__(16) bf16 As[128*32];
    __shared__ __align__(16) bf16 Bs[128*32];
    const int t = threadIdx.x;
    const int colBase = blockIdx.x * 128;
    const int rowBase = blockIdx.y * 128;
    const int w = t >> 6, lane = t & 63, quad = lane >> 4, r16 = lane & 15;
    const int wr = w >> 1, wc = w & 1;
    const int ldsW = w << 6;

    f32x4 acc[4][4];
#pragma unroll
    for (int i = 0; i < 4; ++i)
#pragma unroll
        for (int j = 0; j < 4; ++j) acc[i][j] = (f32x4){0.f,0.f,0.f,0.f};

    for (int k0 = 0; k0 < 768; k0 += 32) {
        int u0 = t, u1 = t + 256;
        async_ld16(&A[(size_t)(rowBase + (u0>>2))*768 + k0 + (u0&3)*8],
                   &As[(size_t)ldsW*8]);
        async_ld16(&A[(size_t)(rowBase + (u1>>2))*768 + k0 + (u1&3)*8],
                   &As[(size_t)(256 + ldsW)*8]);
        async_ld16(&W[(size_t)(colBase + (u0>>2))*768 + k0 + (u0&3)*8],
                   &Bs[(size_t)ldsW*8]);
        async_ld16(&W[(size_t)(colBase + (u1>>2))*768 + k0 + (u1&3)*8],
                   &Bs[(size_t)(256 + ldsW)*8]);
        __syncthreads();
        bf16x8 af[4], bfr[4];
#pragma unroll
        for (int ti = 0; ti < 4; ++ti)
            af[ti] = *(const bf16x8*)(&As[(wr*64 + ti*16 + r16)*32 + quad*8]);
#pragma unroll
        for (int tj = 0; tj < 4; ++tj)
            bfr[tj] = *(const bf16x8*)(&Bs[(wc*64 + tj*16 + r16)*32 + quad*8]);
#pragma unroll
        for (int ti = 0; ti < 4; ++ti)
#pragma unroll
            for (int tj = 0; tj < 4; ++tj)
                acc[ti][tj] = __builtin_amdgcn_mfma_f32_16x16x32_bf16(
                    af[ti], bfr[tj], acc[ti][tj], 0, 0, 0);
        __syncthreads();
    }
#pragma unroll
    for (int tj = 0; tj < 4; ++tj) {
        int col = colBase + wc*64 + tj*16 + r16;
        float bb = bo[col];
#pragma unroll
        for (int ti = 0; ti < 4; ++ti) {
            int row0 = rowBase + wr*64 + ti*16 + quad*4;
#pragma unroll
            for (int rr = 0; rr < 4; ++rr)
                C[(size_t)(row0+rr)*768 + col] = f2bf(acc[ti][tj][rr] + bb);
        }
    }
}

// one block per (m, nh); 256 threads = 4 waves; 4 passes of 64 q rows.
__global__ __launch_bounds__(256, 4)
void attn_kernel(const bf16* __restrict__ qbuf, const bf16* __restrict__ kbuf,
                 bf16* vctx, const int* __restrict__ a_sizes)
{
    __shared__ __align__(16) bf16 VT[64*264];
    __shared__ __align__(16) bf16 P[4*16*264];

    const int b = blockIdx.x;
    const int m = b / NH_, nh = b % NH_;
    const int t = threadIdx.x;
    const int w = t >> 6, lane = t & 63, quad = lane >> 4, r16 = lane & 15;
    const int size = a_sizes[m];
    const size_t headOff = (size_t)m*L_SEQ*768 + nh*64;

    {
        const int k0 = (t & 127) * 2;
        const int dh = (t >> 7) * 32;
        const bf16* v0 = vctx + headOff + (size_t)k0*768 + dh;
        const bf16* v1 = v0 + 768;
        u16x8 r0[4], r1[4];
#pragma unroll
        for (int c = 0; c < 4; ++c) {
            r0[c] = *(const u16x8*)(v0 + c*8);
            r1[c] = *(const u16x8*)(v1 + c*8);
        }
#pragma unroll
        for (int c = 0; c < 4; ++c)
#pragma unroll
            for (int j = 0; j < 8; ++j) {
                unsigned val = (unsigned)r0[c][j] | ((unsigned)r1[c][j] << 16);
                *(unsigned*)(&VT[(size_t)(dh + c*8 + j)*264 + k0]) = val;
            }
    }
    __syncthreads();

    bf16* Pw = P + w*16*264;
    for (int pass = 0; pass < 4; ++pass) {
        const int qrow0 = pass*64 + w*16;
        bf16x8 aq0, aq1;
        {
            const bf16* qrow = qbuf + headOff + (size_t)(qrow0 + r16)*768 + quad*8;
            aq0 = *(const bf16x8*)(qrow);
            aq1 = *(const bf16x8*)(qrow + 32);
        }
        f32x4 S[16];
#pragma unroll
        for (int kt = 0; kt < 16; ++kt) {
            const bf16* krow = kbuf + headOff + (size_t)(kt*16 + r16)*768 + quad*8;
            bf16x8 bk0 = *(const bf16x8*)(krow);
            bf16x8 bk1 = *(const bf16x8*)(krow + 32);
            f32x4 s = (f32x4){0.f,0.f,0.f,0.f};
            s = __builtin_amdgcn_mfma_f32_16x16x32_bf16(aq0, bk0, s, 0, 0, 0);
            s = __builtin_amdgcn_mfma_f32_16x16x32_bf16(aq1, bk1, s, 0, 0, 0);
            S[kt] = s;
        }
        float mrow[4] = {-1e30f,-1e30f,-1e30f,-1e30f};
#pragma unroll
        for (int kt = 0; kt < 16; ++kt) {
            int key = kt*16 + r16;
#pragma unroll
            for (int rr = 0; rr < 4; ++rr) {
                float s = S[kt][rr] * 0.125f;
                if (key >= size) s = -1e9f;
                S[kt][rr] = s;
                mrow[rr] = fmaxf(mrow[rr], s);
            }
        }
#pragma unroll
        for (int msk = 1; msk < 16; msk <<= 1)
#pragma unroll
            for (int rr = 0; rr < 4; ++rr)
                mrow[rr] = fmaxf(mrow[rr], __shfl_xor(mrow[rr], msk));
        float lrow[4] = {0.f,0.f,0.f,0.f};
#pragma unroll
        for (int kt = 0; kt < 16; ++kt) {
#pragma unroll
            for (int rr = 0; rr < 4; ++rr) {
                float p = __expf(S[kt][rr] - mrow[rr]);
                lrow[rr] += p;
                Pw[(quad*4+rr)*264 + kt*16 + r16] = f2bf(p);
            }
        }
#pragma unroll
        for (int msk = 1; msk < 16; msk <<= 1)
#pragma unroll
            for (int rr = 0; rr < 4; ++rr)
                lrow[rr] += __shfl_xor(lrow[rr], msk);
        asm volatile("s_waitcnt lgkmcnt(0)" ::: "memory");

        bf16x8 pa[8];
#pragma unroll
        for (int kb2 = 0; kb2 < 8; ++kb2)
            pa[kb2] = *(const bf16x8*)(&Pw[r16*264 + kb2*32 + quad*8]);
        float inv[4];
#pragma unroll
        for (int rr = 0; rr < 4; ++rr) inv[rr] = 1.f / lrow[rr];
#pragma unroll
        for (int dt = 0; dt < 4; ++dt) {
            f32x4 c = (f32x4){0.f,0.f,0.f,0.f};
#pragma unroll
            for (int kb2 = 0; kb2 < 8; ++kb2) {
                bf16x8 vb8 = *(const bf16x8*)(&VT[(dt*16 + r16)*264 + kb2*32 + quad*8]);
                c = __builtin_amdgcn_mfma_f32_16x16x32_bf16(pa[kb2], vb8, c, 0, 0, 0);
            }
#pragma unroll
            for (int rr = 0; rr < 4; ++rr) {
                int q = qrow0 + quad*4 + rr;
                vctx[headOff + (size_t)q*768 + dt*16 + r16] = f2bf(c[rr] * inv[rr]);
            }
        }
    }
}

__global__ __launch_bounds__(256, 4)
void ln_kernel(const bf16* __restrict__ proj, const float* __restrict__ af,
               const float* __restrict__ gamma, const float* __restrict__ beta,
               const int* __restrict__ a_sizes, float* __restrict__ out)
{
    const int w = threadIdx.x >> 6, lane = threadIdx.x & 63;
    const int n = blockIdx.x * 4 + w;
    const int m = n >> 8, l = n & 255;
    const int size = a_sizes[m];
    float* orow = out + (size_t)n * 768;
    if (l >= size) {
        float4 z = {0.f,0.f,0.f,0.f};
#pragma unroll
        for (int i = 0; i < 3; ++i) *(float4*)(&orow[i*256 + lane*4]) = z;
        return;
    }
    const bf16*  prow = proj + (size_t)n * 768;
    const float* xrow = af   + (size_t)n * 768;
    float y[3][4];
    float s = 0.f;
#pragma unroll
    for (int i = 0; i < 3; ++i) {
        int c = i*256 + lane*4;
        float4 xv = *(const float4*)(&xrow[c]);
        ushort4 pv = *(const ushort4*)(&prow[c]);
        y[i][0] = xv.x + bfbits2f(pv.x);
        y[i][1] = xv.y + bfbits2f(pv.y);
        y[i][2] = xv.z + bfbits2f(pv.z);
        y[i][3] = xv.w + bfbits2f(pv.w);
        s += y[i][0] + y[i][1] + y[i][2] + y[i][3];
    }
#pragma unroll
    for (int msk = 1; msk < 64; msk <<= 1) s += __shfl_xor(s, msk);
    float mu = s * (1.f/768.f);
    float v = 0.f;
#pragma unroll
    for (int i = 0; i < 3; ++i)
#pragma unroll
        for (int j = 0; j < 4; ++j) { float d = y[i][j] - mu; v += d*d; }
#pragma unroll
    for (int msk = 1; msk < 64; msk <<= 1) v += __shfl_xor(v, msk);
    float rstd = rsqrtf(v * (1.f/768.f) + 1e-5f);
#pragma unroll
    for (int i = 0; i < 3; ++i) {
        int c = i*256 + lane*4;
        float4 gv = *(const float4*)(&gamma[c]);
        float4 bv = *(const float4*)(&beta[c]);
        float4 o;
        o.x = (y[i][0] - mu) * rstd * gv.x + bv.x;
        o.y = (y[i][1] - mu) * rstd * gv.y + bv.y;
        o.z = (y[i][2] - mu) * rstd * gv.z + bv.z;
        o.w = (y[i][3] - mu) * rstd * gv.w + bv.w;
        *(float4*)(&orow[c]) = o;
    }
}

extern "C" void kernel_launch(void* const* d_in, const int* in_sizes, int n_in,
                              void* d_out, int out_size, void* d_ws, size_t ws_size,
                              hipStream_t stream)
{
    (void)in_sizes; (void)n_in; (void)out_size; (void)ws_size;
    const float* af    = (const float*)d_in[0];
    const float* Wq    = (const float*)d_in[1];
    const float* bq    = (const float*)d_in[2];
    const float* Wk    = (const float*)d_in[3];
    const float* bk    = (const float*)d_in[4];
    const float* Wv    = (const float*)d_in[5];
    const float* bv    = (const float*)d_in[6];
    const float* Wo    = (const float*)d_in[7];
    const float* bo    = (const float*)d_in[8];
    const float* gamma = (const float*)d_in[9];
    const float* beta  = (const float*)d_in[10];
    const int* a_sizes = (const int*)d_in[12];
    float* outp = (float*)d_out;

    bf16* qb   = (bf16*)d_ws;
    bf16* kb   = qb + (size_t)N_TOT * 768;
    bf16* vb   = kb + (size_t)N_TOT * 768;          // ctx overwrites in place
    bf16* Wcat = vb + (size_t)N_TOT * 768;
    bf16* Wobf = Wcat + (size_t)2304 * 768;

    cvt_w<<<dim3(288, 4), 256, 0, stream>>>(Wq, Wk, Wv, Wo, Wcat, Wobf);
    gemm_qkv<<<dim3(18, 256), 256, 0, stream>>>(af, Wcat, bq, bk, bv, qb, kb, vb);
    attn_kernel<<<dim3(M_MOL * NH_), 256, 0, stream>>>(qb, kb, vb, a_sizes);
    gemm_o<<<dim3(6, 256), 256, 0, stream>>>(vb, Wobf, bo, qb);
    ln_kernel<<<dim3(N_TOT / 4), 256, 0, stream>>>(qb, af, gamma, beta, a_sizes, outp);
}

// Round 4
// 521.781 us; speedup vs baseline: 1.8122x; 1.1881x over previous
//
#include <hip/hip_runtime.h>
#include <hip/hip_bf16.h>
#include <stdint.h>

#define M_MOL 128
#define L_SEQ 256
#define H_DIM 768
#define NH_   12
#define HD_   64
#define N_TOT (M_MOL * L_SEQ)

typedef __attribute__((ext_vector_type(8))) short bf16x8;
typedef __attribute__((ext_vector_type(4))) float f32x4;
typedef __attribute__((ext_vector_type(8))) unsigned short u16x8;
typedef __hip_bfloat16 bf16;

__device__ __forceinline__ float bf2f(bf16 x){ return __bfloat162float(x); }
__device__ __forceinline__ bf16 f2bf(float x){ return __float2bfloat16(x); }
__device__ __forceinline__ float bfbits2f(unsigned short u){
    return __uint_as_float(((unsigned)u) << 16);
}
__device__ __forceinline__ unsigned pk2(float lo, float hi){
    bf16 a = f2bf(lo), b = f2bf(hi);
    unsigned short ua, ub;
    __builtin_memcpy(&ua, &a, 2);
    __builtin_memcpy(&ub, &b, 2);
    return (unsigned)ua | ((unsigned)ub << 16);
}

typedef const __attribute__((address_space(1))) unsigned int* as1_u32p;
typedef __attribute__((address_space(3))) unsigned int* as3_u32p;
__device__ __forceinline__ void async_ld16(const void* g, const void* l) {
    __builtin_amdgcn_global_load_lds((as1_u32p)(unsigned long long)g,
                                     (as3_u32p)(unsigned int)(unsigned long long)l,
                                     16, 0, 0);
}

// one kernel converts atom_features (12288 blocks) + 4 weight mats (288 each)
__global__ __launch_bounds__(256)
void cvt_all(const float* __restrict__ af, const float* __restrict__ Wq,
             const float* __restrict__ Wk, const float* __restrict__ Wv,
             const float* __restrict__ Wo,
             bf16* __restrict__ afb, bf16* __restrict__ Wcat, bf16* __restrict__ Wobf)
{
    const int b = blockIdx.x;
    const float* src; bf16* dst; int local;
    if (b < 12288) { src = af; dst = afb; local = b; }
    else {
        int r = b - 12288;
        int mat = r / 288; local = r % 288;
        src = mat==0 ? Wq : mat==1 ? Wk : mat==2 ? Wv : Wo;
        dst = (mat < 3) ? (Wcat + (size_t)mat*589824) : Wobf;
    }
    const size_t off = ((size_t)local*256 + threadIdx.x)*8;
    float4 a = *(const float4*)(src + off);
    float4 c = *(const float4*)(src + off + 4);
    uint4 o = { pk2(a.x,a.y), pk2(a.z,a.w), pk2(c.x,c.y), pk2(c.z,c.w) };
    *(uint4*)(dst + off) = o;
}

// fused QKV GEMM, all-bf16, async staging; grid 4608: col = b/256 (slow), row = b%256
__global__ __launch_bounds__(256, 2)
void gemm_qkv(const bf16* __restrict__ A, const bf16* __restrict__ W,
              const float* __restrict__ bq, const float* __restrict__ bk,
              const float* __restrict__ bv,
              bf16* __restrict__ qb, bf16* __restrict__ kb, bf16* __restrict__ vb)
{
    __shared__ __align__(16) bf16 As[128*32];
    __shared__ __align__(16) bf16 Bs[128*32];
    const int t = threadIdx.x;
    const int colBlk  = blockIdx.x >> 8;          // 0..17, slow
    const int rowBase = (blockIdx.x & 255) * 128; // fast
    const int colBase = colBlk * 128;
    const int w = t >> 6, lane = t & 63, quad = lane >> 4, r16 = lane & 15;
    const int wr = w >> 1, wc = w & 1;
    const int ldsW = w << 6;

    f32x4 acc[4][4];
#pragma unroll
    for (int i = 0; i < 4; ++i)
#pragma unroll
        for (int j = 0; j < 4; ++j) acc[i][j] = (f32x4){0.f,0.f,0.f,0.f};

    for (int k0 = 0; k0 < 768; k0 += 32) {
        int u0 = t, u1 = t + 256;
        async_ld16(&A[(size_t)(rowBase + (u0>>2))*768 + k0 + (u0&3)*8],
                   &As[(size_t)ldsW*8]);
        async_ld16(&A[(size_t)(rowBase + (u1>>2))*768 + k0 + (u1&3)*8],
                   &As[(size_t)(256 + ldsW)*8]);
        async_ld16(&W[(size_t)(colBase + (u0>>2))*768 + k0 + (u0&3)*8],
                   &Bs[(size_t)ldsW*8]);
        async_ld16(&W[(size_t)(colBase + (u1>>2))*768 + k0 + (u1&3)*8],
                   &Bs[(size_t)(256 + ldsW)*8]);
        __syncthreads();
        bf16x8 af[4], bfr[4];
#pragma unroll
        for (int ti = 0; ti < 4; ++ti)
            af[ti] = *(const bf16x8*)(&As[(wr*64 + ti*16 + r16)*32 + quad*8]);
#pragma unroll
        for (int tj = 0; tj < 4; ++tj)
            bfr[tj] = *(const bf16x8*)(&Bs[(wc*64 + tj*16 + r16)*32 + quad*8]);
#pragma unroll
        for (int ti = 0; ti < 4; ++ti)
#pragma unroll
            for (int tj = 0; tj < 4; ++tj)
                acc[ti][tj] = __builtin_amdgcn_mfma_f32_16x16x32_bf16(
                    af[ti], bfr[tj], acc[ti][tj], 0, 0, 0);
        __syncthreads();
    }
    const int sel = colBlk / 6;                  // 0=q 1=k 2=v
    const float* bias = sel==0 ? bq : sel==1 ? bk : bv;
    bf16* C = sel==0 ? qb : sel==1 ? kb : vb;
    const int colSec = colBase - sel*768;
#pragma unroll
    for (int tj = 0; tj < 4; ++tj) {
        int col = colSec + wc*64 + tj*16 + r16;
        float bb = bias[col];
#pragma unroll
        for (int ti = 0; ti < 4; ++ti) {
            int row0 = rowBase + wr*64 + ti*16 + quad*4;
#pragma unroll
            for (int rr = 0; rr < 4; ++rr)
                C[(size_t)(row0+rr)*768 + col] = f2bf(acc[ti][tj][rr] + bb);
        }
    }
}

// Wo projection, all-bf16; grid 1536: col = b/256 (slow, 0..5), row = b%256
__global__ __launch_bounds__(256, 2)
void gemm_o(const bf16* __restrict__ A, const bf16* __restrict__ W,
            const float* __restrict__ bo, bf16* __restrict__ C)
{
    __shared__ __align__(16) bf16 As[128*32];
    __shared__ __align__(16) bf16 Bs[128*32];
    const int t = threadIdx.x;
    const int colBase = (blockIdx.x >> 8) * 128;
    const int rowBase = (blockIdx.x & 255) * 128;
    const int w = t >> 6, lane = t & 63, quad = lane >> 4, r16 = lane & 15;
    const int wr = w >> 1, wc = w & 1;
    const int ldsW = w << 6;

    f32x4 acc[4][4];
#pragma unroll
    for (int i = 0; i < 4; ++i)
#pragma unroll
        for (int j = 0; j < 4; ++j) acc[i][j] = (f32x4){0.f,0.f,0.f,0.f};

    for (int k0 = 0; k0 < 768; k0 += 32) {
        int u0 = t, u1 = t + 256;
        async_ld16(&A[(size_t)(rowBase + (u0>>2))*768 + k0 + (u0&3)*8],
                   &As[(size_t)ldsW*8]);
        async_ld16(&A[(size_t)(rowBase + (u1>>2))*768 + k0 + (u1&3)*8],
                   &As[(size_t)(256 + ldsW)*8]);
        async_ld16(&W[(size_t)(colBase + (u0>>2))*768 + k0 + (u0&3)*8],
                   &Bs[(size_t)ldsW*8]);
        async_ld16(&W[(size_t)(colBase + (u1>>2))*768 + k0 + (u1&3)*8],
                   &Bs[(size_t)(256 + ldsW)*8]);
        __syncthreads();
        bf16x8 af[4], bfr[4];
#pragma unroll
        for (int ti = 0; ti < 4; ++ti)
            af[ti] = *(const bf16x8*)(&As[(wr*64 + ti*16 + r16)*32 + quad*8]);
#pragma unroll
        for (int tj = 0; tj < 4; ++tj)
            bfr[tj] = *(const bf16x8*)(&Bs[(wc*64 + tj*16 + r16)*32 + quad*8]);
#pragma unroll
        for (int ti = 0; ti < 4; ++ti)
#pragma unroll
            for (int tj = 0; tj < 4; ++tj)
                acc[ti][tj] = __builtin_amdgcn_mfma_f32_16x16x32_bf16(
                    af[ti], bfr[tj], acc[ti][tj], 0, 0, 0);
        __syncthreads();
    }
#pragma unroll
    for (int tj = 0; tj < 4; ++tj) {
        int col = colBase + wc*64 + tj*16 + r16;
        float bb = bo[col];
#pragma unroll
        for (int ti = 0; ti < 4; ++ti) {
            int row0 = rowBase + wr*64 + ti*16 + quad*4;
#pragma unroll
            for (int rr = 0; rr < 4; ++rr)
                C[(size_t)(row0+rr)*768 + col] = f2bf(acc[ti][tj][rr] + bb);
        }
    }
}

// one block per (m, nh); 256 threads = 4 waves; 4 passes of 64 q rows.
// K fragments hoisted into registers (loaded once, reused all 4 passes).
__global__ __launch_bounds__(256, 2)
void attn_kernel(const bf16* __restrict__ qbuf, const bf16* __restrict__ kbuf,
                 bf16* vctx, const int* __restrict__ a_sizes)
{
    __shared__ __align__(16) bf16 VT[64*264];
    __shared__ __align__(16) bf16 P[4*16*264];

    const int b = blockIdx.x;
    const int m = b / NH_, nh = b % NH_;
    const int t = threadIdx.x;
    const int w = t >> 6, lane = t & 63, quad = lane >> 4, r16 = lane & 15;
    const int size = a_sizes[m];
    const size_t headOff = (size_t)m*L_SEQ*768 + nh*64;

    {
        const int k0 = (t & 127) * 2;
        const int dh = (t >> 7) * 32;
        const bf16* v0 = vctx + headOff + (size_t)k0*768 + dh;
        const bf16* v1 = v0 + 768;
        u16x8 r0[4], r1[4];
#pragma unroll
        for (int c = 0; c < 4; ++c) {
            r0[c] = *(const u16x8*)(v0 + c*8);
            r1[c] = *(const u16x8*)(v1 + c*8);
        }
#pragma unroll
        for (int c = 0; c < 4; ++c)
#pragma unroll
            for (int j = 0; j < 8; ++j) {
                unsigned val = (unsigned)r0[c][j] | ((unsigned)r1[c][j] << 16);
                *(unsigned*)(&VT[(size_t)(dh + c*8 + j)*264 + k0]) = val;
            }
    }
    __syncthreads();

    // hoist K fragments: full head K-slice per wave, once
    bf16x8 kf0[16], kf1[16];
#pragma unroll
    for (int kt = 0; kt < 16; ++kt) {
        const bf16* krow = kbuf + headOff + (size_t)(kt*16 + r16)*768 + quad*8;
        kf0[kt] = *(const bf16x8*)(krow);
        kf1[kt] = *(const bf16x8*)(krow + 32);
    }

    bf16* Pw = P + w*16*264;
    for (int pass = 0; pass < 4; ++pass) {
        const int qrow0 = pass*64 + w*16;
        bf16x8 aq0, aq1;
        {
            const bf16* qrow = qbuf + headOff + (size_t)(qrow0 + r16)*768 + quad*8;
            aq0 = *(const bf16x8*)(qrow);
            aq1 = *(const bf16x8*)(qrow + 32);
        }
        f32x4 S[16];
#pragma unroll
        for (int kt = 0; kt < 16; ++kt) {
            f32x4 s = (f32x4){0.f,0.f,0.f,0.f};
            s = __builtin_amdgcn_mfma_f32_16x16x32_bf16(aq0, kf0[kt], s, 0, 0, 0);
            s = __builtin_amdgcn_mfma_f32_16x16x32_bf16(aq1, kf1[kt], s, 0, 0, 0);
            S[kt] = s;
        }
        float mrow[4] = {-1e30f,-1e30f,-1e30f,-1e30f};
#pragma unroll
        for (int kt = 0; kt < 16; ++kt) {
            int key = kt*16 + r16;
#pragma unroll
            for (int rr = 0; rr < 4; ++rr) {
                float s = S[kt][rr] * 0.125f;
                if (key >= size) s = -1e9f;
                S[kt][rr] = s;
                mrow[rr] = fmaxf(mrow[rr], s);
            }
        }
#pragma unroll
        for (int msk = 1; msk < 16; msk <<= 1)
#pragma unroll
            for (int rr = 0; rr < 4; ++rr)
                mrow[rr] = fmaxf(mrow[rr], __shfl_xor(mrow[rr], msk));
        float lrow[4] = {0.f,0.f,0.f,0.f};
#pragma unroll
        for (int kt = 0; kt < 16; ++kt) {
#pragma unroll
            for (int rr = 0; rr < 4; ++rr) {
                float p = __expf(S[kt][rr] - mrow[rr]);
                lrow[rr] += p;
                Pw[(quad*4+rr)*264 + kt*16 + r16] = f2bf(p);
            }
        }
#pragma unroll
        for (int msk = 1; msk < 16; msk <<= 1)
#pragma unroll
            for (int rr = 0; rr < 4; ++rr)
                lrow[rr] += __shfl_xor(lrow[rr], msk);
        asm volatile("s_waitcnt lgkmcnt(0)" ::: "memory");

        bf16x8 pa[8];
#pragma unroll
        for (int kb2 = 0; kb2 < 8; ++kb2)
            pa[kb2] = *(const bf16x8*)(&Pw[r16*264 + kb2*32 + quad*8]);
        float inv[4];
#pragma unroll
        for (int rr = 0; rr < 4; ++rr) inv[rr] = 1.f / lrow[rr];
#pragma unroll
        for (int dt = 0; dt < 4; ++dt) {
            f32x4 c = (f32x4){0.f,0.f,0.f,0.f};
#pragma unroll
            for (int kb2 = 0; kb2 < 8; ++kb2) {
                bf16x8 vb8 = *(const bf16x8*)(&VT[(dt*16 + r16)*264 + kb2*32 + quad*8]);
                c = __builtin_amdgcn_mfma_f32_16x16x32_bf16(pa[kb2], vb8, c, 0, 0, 0);
            }
#pragma unroll
            for (int rr = 0; rr < 4; ++rr) {
                int q = qrow0 + quad*4 + rr;
                vctx[headOff + (size_t)q*768 + dt*16 + r16] = f2bf(c[rr] * inv[rr]);
            }
        }
    }
}

__global__ __launch_bounds__(256, 4)
void ln_kernel(const bf16* __restrict__ proj, const float* __restrict__ af,
               const float* __restrict__ gamma, const float* __restrict__ beta,
               const int* __restrict__ a_sizes, float* __restrict__ out)
{
    const int w = threadIdx.x >> 6, lane = threadIdx.x & 63;
    const int n = blockIdx.x * 4 + w;
    const int m = n >> 8, l = n & 255;
    const int size = a_sizes[m];
    float* orow = out + (size_t)n * 768;
    if (l >= size) {
        float4 z = {0.f,0.f,0.f,0.f};
#pragma unroll
        for (int i = 0; i < 3; ++i) *(float4*)(&orow[i*256 + lane*4]) = z;
        return;
    }
    const bf16*  prow = proj + (size_t)n * 768;
    const float* xrow = af   + (size_t)n * 768;
    float y[3][4];
    float s = 0.f;
#pragma unroll
    for (int i = 0; i < 3; ++i) {
        int c = i*256 + lane*4;
        float4 xv = *(const float4*)(&xrow[c]);
        ushort4 pv = *(const ushort4*)(&prow[c]);
        y[i][0] = xv.x + bfbits2f(pv.x);
        y[i][1] = xv.y + bfbits2f(pv.y);
        y[i][2] = xv.z + bfbits2f(pv.z);
        y[i][3] = xv.w + bfbits2f(pv.w);
        s += y[i][0] + y[i][1] + y[i][2] + y[i][3];
    }
#pragma unroll
    for (int msk = 1; msk < 64; msk <<= 1) s += __shfl_xor(s, msk);
    float mu = s * (1.f/768.f);
    float v = 0.f;
#pragma unroll
    for (int i = 0; i < 3; ++i)
#pragma unroll
        for (int j = 0; j < 4; ++j) { float d = y[i][j] - mu; v += d*d; }
#pragma unroll
    for (int msk = 1; msk < 64; msk <<= 1) v += __shfl_xor(v, msk);
    float rstd = rsqrtf(v * (1.f/768.f) + 1e-5f);
#pragma unroll
    for (int i = 0; i < 3; ++i) {
        int c = i*256 + lane*4;
        float4 gv = *(const float4*)(&gamma[c]);
        float4 bv = *(const float4*)(&beta[c]);
        float4 o;
        o.x = (y[i][0] - mu) * rstd * gv.x + bv.x;
        o.y = (y[i][1] - mu) * rstd * gv.y + bv.y;
        o.z = (y[i][2] - mu) * rstd * gv.z + bv.z;
        o.w = (y[i][3] - mu) * rstd * gv.w + bv.w;
        *(float4*)(&orow[c]) = o;
    }
}

extern "C" void kernel_launch(void* const* d_in, const int* in_sizes, int n_in,
                              void* d_out, int out_size, void* d_ws, size_t ws_size,
                              hipStream_t stream)
{
    (void)in_sizes; (void)n_in; (void)out_size; (void)ws_size;
    const float* af    = (const float*)d_in[0];
    const float* Wq    = (const float*)d_in[1];
    const float* bq    = (const float*)d_in[2];
    const float* Wk    = (const float*)d_in[3];
    const float* bk    = (const float*)d_in[4];
    const float* Wv    = (const float*)d_in[5];
    const float* bv    = (const float*)d_in[6];
    const float* Wo    = (const float*)d_in[7];
    const float* bo    = (const float*)d_in[8];
    const float* gamma = (const float*)d_in[9];
    const float* beta  = (const float*)d_in[10];
    const int* a_sizes = (const int*)d_in[12];
    float* outp = (float*)d_out;

    // d_ws: qb, kb, vb (bf16 N x 768 each = 144 MiB; proven ws >= 192 MiB)
    bf16* qb = (bf16*)d_ws;
    bf16* kb = qb + (size_t)N_TOT * 768;
    bf16* vb = kb + (size_t)N_TOT * 768;          // ctx overwrites in place
    // d_out doubles as scratch until ln_kernel overwrites it (stream-ordered):
    // afb 50.3 MB + Wcat 3.4 MB + Wobf 1.1 MB < 100.6 MB output buffer
    bf16* afb  = (bf16*)d_out;
    bf16* Wcat = afb + (size_t)N_TOT * 768;
    bf16* Wobf = Wcat + (size_t)2304 * 768;

    cvt_all<<<dim3(12288 + 4*288), 256, 0, stream>>>(af, Wq, Wk, Wv, Wo, afb, Wcat, Wobf);
    gemm_qkv<<<dim3(18*256), 256, 0, stream>>>(afb, Wcat, bq, bk, bv, qb, kb, vb);
    attn_kernel<<<dim3(M_MOL * NH_), 256, 0, stream>>>(qb, kb, vb, a_sizes);
    gemm_o<<<dim3(6*256), 256, 0, stream>>>(vb, Wobf, bo, qb);
    ln_kernel<<<dim3(N_TOT / 4), 256, 0, stream>>>(qb, af, gamma, beta, a_sizes, outp);
}